// Round 3
// baseline (240.888 us; speedup 1.0000x reference)
//
#include <hip/hip_runtime.h>
#include <math.h>

namespace {
constexpr int B_ = 32, S_ = 1024, D_ = 256, N_ = 32, C_ = 64;
constexpr int NC_ = N_ * C_;    // 2048
constexpr int ROWS_ = B_ * S_;  // 32768

typedef __bf16 bf16x8 __attribute__((ext_vector_type(8)));
typedef __bf16 bf16x4 __attribute__((ext_vector_type(4)));
typedef float floatx4 __attribute__((ext_vector_type(4)));

__device__ __forceinline__ float bflo(unsigned int u) {
  union { unsigned int i; float f; } v; v.i = u << 16; return v.f;
}
__device__ __forceinline__ float bfhi(unsigned int u) {
  union { unsigned int i; float f; } v; v.i = u & 0xffff0000u; return v.f;
}
__device__ __forceinline__ void async16(const void* g, void* l) {
  __builtin_amdgcn_global_load_lds(
      (const __attribute__((address_space(1))) void*)g,
      (__attribute__((address_space(3))) void*)l, 16, 0, 0);
}
__device__ __forceinline__ void unpack8(uint4 u, float* o) {
  o[0] = bflo(u.x); o[1] = bfhi(u.x); o[2] = bflo(u.y); o[3] = bfhi(u.y);
  o[4] = bflo(u.z); o[5] = bfhi(u.z); o[6] = bflo(u.w); o[7] = bfhi(u.w);
}
}  // namespace

// K0: Wt[n][c][d] = bf16(W[n][d][c])  (B^T layout, k contiguous)
extern "C" __global__ __launch_bounds__(256) void k_convW(
    const float* __restrict__ W, __bf16* __restrict__ Wt) {
  const int n = blockIdx.x, d0 = blockIdx.y * 64;
  __shared__ float tile[64][65];
  const int t = threadIdx.x;
  #pragma unroll
  for (int i = 0; i < 16; ++i) {
    int e = i * 256 + t;
    int dd = e >> 6, c = e & 63;
    tile[dd][c] = W[(size_t)n * (D_ * C_) + (size_t)(d0 + dd) * C_ + c];
  }
  __syncthreads();
  #pragma unroll
  for (int i = 0; i < 16; ++i) {
    int e = i * 256 + t;
    int c = e >> 6, dd = e & 63;
    Wt[(size_t)(n * 64 + c) * D_ + d0 + dd] = (__bf16)tile[dd][c];
  }
}

// K1: u_hat = x @ W  (bf16 MFMA), 128x128 tile, BK=64, fused s1-partial.
// MFMA called with operands SWAPPED (D^T): lane&15 = s-row, quad*4+reg = col.
// => each thread's 4 acc regs are 4 consecutive cols -> 8B bf16x4 stores.
// LDS chunk swizzle: content (row, kcg) stored at linear chunk row*8 + (kcg^(row&7)).
extern "C" __global__ __launch_bounds__(256) void k_gemm(
    const float* __restrict__ x, const __bf16* __restrict__ Wt,
    __bf16* __restrict__ uhat, float* __restrict__ sbuf) {
  __shared__ __align__(16) __bf16 As[128 * 64];
  __shared__ __align__(16) __bf16 Bs[128 * 64];
  __shared__ float sred[2][128];
  const int t = threadIdx.x;
  const int col0 = blockIdx.x * 128;
  const int row0 = blockIdx.y * 128;
  const int w = t >> 6, lane = t & 63, quad = lane >> 4, l16 = lane & 15;
  const int rw0 = (w & 1) * 64, cw0 = (w >> 1) * 64;

  const float* gA[4];
  const __bf16* gB[4];
  __bf16* lA[4];
  __bf16* lB[4];
  #pragma unroll
  for (int i = 0; i < 4; ++i) {
    int L = i * 256 + t;
    int r = L >> 3, kcl = L & 7, kcg = kcl ^ (r & 7);
    gA[i] = x + (size_t)(row0 + r) * D_ + kcg * 8;
    gB[i] = Wt + (size_t)(col0 + r) * D_ + kcg * 8;
    lA[i] = As + L * 8;
    lB[i] = Bs + L * 8;
  }
  int aoff[4][2], boff[4][2];
  #pragma unroll
  for (int i = 0; i < 4; ++i) {
    int m = rw0 + i * 16 + l16;
    int c = cw0 + i * 16 + l16;
    #pragma unroll
    for (int ks = 0; ks < 2; ++ks) {
      int kcg = ks * 4 + quad;
      aoff[i][ks] = (m * 8 + (kcg ^ (m & 7))) * 8;
      boff[i][ks] = (c * 8 + (kcg ^ (c & 7))) * 8;
    }
  }

  floatx4 acc[4][4];  // acc[i][j]: row-group i (row = l16), col-group j (col = quad*4+reg)
  #pragma unroll
  for (int i = 0; i < 4; ++i)
    #pragma unroll
    for (int j = 0; j < 4; ++j)
      acc[i][j] = (floatx4){0.f, 0.f, 0.f, 0.f};

  for (int kk = 0; kk < D_; kk += 64) {
    #pragma unroll
    for (int i = 0; i < 4; ++i) async16(gB[i] + kk, lB[i]);  // B: async DMA
    #pragma unroll
    for (int i = 0; i < 4; ++i) {                            // A: load+cvt+write
      float4 f0 = *(const float4*)(gA[i] + kk);
      float4 f1 = *(const float4*)(gA[i] + kk + 4);
      bf16x8 p;
      p[0] = (__bf16)f0.x; p[1] = (__bf16)f0.y; p[2] = (__bf16)f0.z; p[3] = (__bf16)f0.w;
      p[4] = (__bf16)f1.x; p[5] = (__bf16)f1.y; p[6] = (__bf16)f1.z; p[7] = (__bf16)f1.w;
      *(bf16x8*)lA[i] = p;
    }
    __syncthreads();
    #pragma unroll
    for (int ks = 0; ks < 2; ++ks) {
      bf16x8 af[4], bfr[4];
      #pragma unroll
      for (int i = 0; i < 4; ++i) af[i] = *(const bf16x8*)(As + aoff[i][ks]);
      #pragma unroll
      for (int j = 0; j < 4; ++j) bfr[j] = *(const bf16x8*)(Bs + boff[j][ks]);
      #pragma unroll
      for (int i = 0; i < 4; ++i)
        #pragma unroll
        for (int j = 0; j < 4; ++j)
          acc[i][j] = __builtin_amdgcn_mfma_f32_16x16x32_bf16(bfr[j], af[i], acc[i][j], 0, 0, 0);
    }
    __syncthreads();
  }

  // Epilogue: coalesced-ish bf16x4 stores + fused s1 column-sum partial.
  const int b_idx = row0 >> 10;
  #pragma unroll
  for (int j = 0; j < 4; ++j) {
    const int col_g = col0 + cw0 + j * 16 + quad * 4;
    float cs[4] = {0.f, 0.f, 0.f, 0.f};
    #pragma unroll
    for (int i = 0; i < 4; ++i) {
      const int row_g = row0 + rw0 + i * 16 + l16;
      bf16x4 o;
      #pragma unroll
      for (int r = 0; r < 4; ++r) {
        float vv = acc[i][j][r];
        cs[r] += vv;
        o[r] = (__bf16)vv;
      }
      *(bf16x4*)&uhat[(size_t)row_g * NC_ + col_g] = o;
    }
    #pragma unroll
    for (int r = 0; r < 4; ++r) {
      // reduce over the 16 rows (l16 lanes) within this quad
      #pragma unroll
      for (int m = 1; m <= 8; m <<= 1) cs[r] += __shfl_xor(cs[r], m);
      if (l16 == 0) sred[w & 1][cw0 + j * 16 + quad * 4 + r] = cs[r];
    }
  }
  __syncthreads();
  if (t < 128) {
    float ssum = (sred[0][t] + sred[1][t]) * (1.0f / 32.0f);
    atomicAdd(&sbuf[b_idx * NC_ + col0 + t], ssum);
  }
}

// K2: one routing pass. Each wave owns whole s-rows; lane covers 32 contiguous
// (n,c): n = lane>>1. nv=1: logit = u.v1; nv=2: logit = u.v1 + u.v2 (recomputed,
// bit-identical to pass 1 -> no logits buffer). c = softmax over n; acc c*u_hat.
extern "C" __global__ __launch_bounds__(256) void k_route(
    const unsigned short* __restrict__ uhat, const float* __restrict__ v1,
    const float* __restrict__ v2, float* __restrict__ s_out, int nv) {
  const int b = blockIdx.x, chunk = blockIdx.y;
  const int t = threadIdx.x, w = t >> 6, lane = t & 63;
  __shared__ float red[4][NC_];

  float vr1[32], vr2[32];
  #pragma unroll
  for (int q = 0; q < 8; ++q) {
    float4 f = *(const float4*)&v1[b * NC_ + lane * 32 + q * 4];
    vr1[q * 4 + 0] = f.x; vr1[q * 4 + 1] = f.y;
    vr1[q * 4 + 2] = f.z; vr1[q * 4 + 3] = f.w;
  }
  if (nv == 2) {
    #pragma unroll
    for (int q = 0; q < 8; ++q) {
      float4 f = *(const float4*)&v2[b * NC_ + lane * 32 + q * 4];
      vr2[q * 4 + 0] = f.x; vr2[q * 4 + 1] = f.y;
      vr2[q * 4 + 2] = f.z; vr2[q * 4 + 3] = f.w;
    }
  }
  float accr[32];
  #pragma unroll
  for (int j = 0; j < 32; ++j) accr[j] = 0.f;

  for (int si = 0; si < 8; ++si) {
    const int s = chunk * 32 + w * 8 + si;
    const size_t base = (size_t)(b * S_ + s) * NC_ + lane * 32;
    uint4 u0 = *(const uint4*)(uhat + base);
    uint4 u1 = *(const uint4*)(uhat + base + 8);
    uint4 u2 = *(const uint4*)(uhat + base + 16);
    uint4 u3 = *(const uint4*)(uhat + base + 24);
    float uf[32];
    unpack8(u0, uf); unpack8(u1, uf + 8); unpack8(u2, uf + 16); unpack8(u3, uf + 24);
    float pd = 0.f;
    #pragma unroll
    for (int j = 0; j < 32; ++j) pd += uf[j] * vr1[j];
    if (nv == 2) {
      float pd2 = 0.f;
      #pragma unroll
      for (int j = 0; j < 32; ++j) pd2 += uf[j] * vr2[j];
      pd += pd2;
    }
    pd += __shfl_xor(pd, 1);  // full 64-c agreement for this n
    float lg = pd;
    float mx = lg;
    #pragma unroll
    for (int m = 2; m <= 32; m <<= 1) mx = fmaxf(mx, __shfl_xor(mx, m));
    float e = __expf(lg - mx);
    float se = e;
    #pragma unroll
    for (int m = 2; m <= 32; m <<= 1) se += __shfl_xor(se, m);
    float wgt = e / se;
    #pragma unroll
    for (int j = 0; j < 32; ++j) accr[j] += wgt * uf[j];
  }
  #pragma unroll
  for (int q = 0; q < 8; ++q) {
    float4 f;
    f.x = accr[q * 4]; f.y = accr[q * 4 + 1];
    f.z = accr[q * 4 + 2]; f.w = accr[q * 4 + 3];
    *(float4*)&red[w][lane * 32 + q * 4] = f;
  }
  __syncthreads();
  #pragma unroll
  for (int q = 0; q < 8; ++q) {
    int f = q * 256 + t;
    float sv = red[0][f] + red[1][f] + red[2][f] + red[3][f];
    atomicAdd(&s_out[b * NC_ + f], sv);
  }
}

// K3: squash along C; also re-zeroes s_in for the next accumulation pass.
extern "C" __global__ __launch_bounds__(64) void k_squash(
    float* __restrict__ s_in, float* __restrict__ v_out) {
  const int bn = blockIdx.x;
  const int lane = threadIdx.x;
  float val = s_in[bn * C_ + lane];
  float sq = val * val;
  #pragma unroll
  for (int m = 32; m; m >>= 1) sq += __shfl_xor(sq, m);
  float scale = sq / ((1.f + sq) * sqrtf(sq + 1e-8f));
  v_out[bn * C_ + lane] = val * scale;
  s_in[bn * C_ + lane] = 0.f;
}

extern "C" void kernel_launch(void* const* d_in, const int* in_sizes, int n_in,
                              void* d_out, int out_size, void* d_ws, size_t ws_size,
                              hipStream_t stream) {
  const float* x = (const float*)d_in[0];   // [B,S,D]
  const float* W = (const float*)d_in[1];   // [N,D,C]
  float* out = (float*)d_out;               // [B,N,C]

  // Workspace layout (~136 MiB total):
  char* ws = (char*)d_ws;
  __bf16* uhat = (__bf16*)ws;                                  // 134,217,728 B
  __bf16* Wt = (__bf16*)(ws + (size_t)ROWS_ * NC_ * 2);        // 1,048,576 B
  float* sbuf = (float*)(ws + (size_t)ROWS_ * NC_ * 2 + (size_t)N_ * D_ * C_ * 2);
  float* v1 = sbuf + B_ * NC_;                                 // 262,144 B
  float* v2 = v1 + B_ * NC_;                                   // 262,144 B

  // 0) W -> Wt (bf16, [n][c][d]); zero sbuf for the gemm's fused s1 atomics
  k_convW<<<dim3(N_, 4), 256, 0, stream>>>(W, Wt);
  hipMemsetAsync(sbuf, 0, (size_t)B_ * NC_ * sizeof(float), stream);

  // 1) GEMM + fused iter-0 s-sum; squash -> v1 (and re-zero sbuf)
  k_gemm<<<dim3(NC_ / 128, ROWS_ / 128), 256, 0, stream>>>(x, Wt, uhat, sbuf);
  k_squash<<<B_ * N_, 64, 0, stream>>>(sbuf, v1);

  // 2) iter 1: c2 = softmax(u.v1); s2; squash -> v2 (and re-zero sbuf)
  k_route<<<dim3(B_, S_ / 32), 256, 0, stream>>>((const unsigned short*)uhat,
                                                 v1, v2, sbuf, 1);
  k_squash<<<B_ * N_, 64, 0, stream>>>(sbuf, v2);

  // 3) iter 2: c3 = softmax(u.v1 + u.v2); s3; squash -> out
  k_route<<<dim3(B_, S_ / 32), 256, 0, stream>>>((const unsigned short*)uhat,
                                                 v1, v2, sbuf, 2);
  k_squash<<<B_ * N_, 64, 0, stream>>>(sbuf, out);
}

// Round 4
// 160.610 us; speedup vs baseline: 1.4998x; 1.4998x over previous
//
#include <hip/hip_runtime.h>
#include <math.h>

namespace {
constexpr int B_ = 32, S_ = 1024, D_ = 256, N_ = 32, C_ = 64;
constexpr int NC_ = N_ * C_;      // 2048
constexpr int CHUNKS_ = 16;       // k_pass s-chunks
constexpr int SCHUNK_ = 64;       // s-rows per k_pass block
constexpr int XP_ = 16;           // xsum partial count

typedef __bf16 bf16x8 __attribute__((ext_vector_type(8)));
typedef __bf16 bf16x4 __attribute__((ext_vector_type(4)));
typedef float floatx4 __attribute__((ext_vector_type(4)));

constexpr int XS_ = 264;  // x_lds row stride (elems)
constexpr int TS_ = 264;  // t_lds row stride
constexpr int CS_ = 72;   // c_T row stride (s-dim 64 + 8 pad)
}  // namespace

// K1: xsum_part[b][sb][d] = sum over 64 s-rows of x[b,s,d]
extern "C" __global__ __launch_bounds__(256) void k_xsum(
    const float* __restrict__ x, float* __restrict__ xsum_part) {
  const int b = blockIdx.x, sb = blockIdx.y, t = threadIdx.x;
  const float* xb = x + ((size_t)b * S_ + sb * 64) * D_;
  float a = 0.f;
  #pragma unroll 8
  for (int s = 0; s < 64; ++s) a += xb[s * D_ + t];
  xsum_part[((size_t)b * XP_ + sb) * D_ + t] = a;
}

// K2 (small chain): per (b,n):
//   zloc[d] = sum_p z[b,p,n,d]            (P partials)
//   s[c]    = scale * sum_d zloc[d]*W[n,d,c];  v = squash(s)
//   if final: write v to vout
//   else:     t = W[n] @ v  (fp32, += old if accum), write t_fp + bf16 hi/lo
extern "C" __global__ __launch_bounds__(256) void k_small(
    const float* __restrict__ z, const float* __restrict__ W,
    float* __restrict__ t_fp, __bf16* __restrict__ t_bhi,
    __bf16* __restrict__ t_blo, float* __restrict__ vout,
    int P, int zb, int zp, int zn, float scale, int accum, int final_) {
  __shared__ float zloc[256];
  __shared__ float sq_red[4][64];
  __shared__ float v_lds[64];
  const int b = blockIdx.x, n = blockIdx.y, t = threadIdx.x;

  float a = 0.f;
  for (int p = 0; p < P; ++p) a += z[(size_t)b * zb + (size_t)p * zp + n * zn + t];
  zloc[t] = a;
  __syncthreads();

  const int c = t & 63, dq = t >> 6;
  const float* Wn = W + (size_t)n * (D_ * C_);
  float s = 0.f;
  #pragma unroll 8
  for (int dd = 0; dd < 64; ++dd) {
    int d = dq * 64 + dd;
    s += zloc[d] * Wn[d * 64 + c];
  }
  sq_red[dq][c] = s;
  __syncthreads();

  if (t < 64) {
    float sc = (sq_red[0][t] + sq_red[1][t] + sq_red[2][t] + sq_red[3][t]) * scale;
    float sq = sc * sc;
    #pragma unroll
    for (int m = 1; m <= 32; m <<= 1) sq += __shfl_xor(sq, m);
    float scl = sq / ((1.f + sq) * sqrtf(sq + 1e-8f));
    float v = sc * scl;
    v_lds[t] = v;
    if (final_) vout[(size_t)b * NC_ + n * 64 + t] = v;
  }
  __syncthreads();

  if (!final_) {
    const float4* W4 = (const float4*)W + (size_t)n * 4096 + t * 16;
    float acc = 0.f;
    #pragma unroll
    for (int q = 0; q < 16; ++q) {
      float4 wv = W4[q];
      acc += wv.x * v_lds[q * 4] + wv.y * v_lds[q * 4 + 1] +
             wv.z * v_lds[q * 4 + 2] + wv.w * v_lds[q * 4 + 3];
    }
    size_t idx = ((size_t)b * N_ + n) * D_ + t;
    float tf = acc + (accum ? t_fp[idx] : 0.f);
    t_fp[idx] = tf;
    __bf16 hi = (__bf16)tf;
    t_bhi[idx] = hi;
    t_blo[idx] = (__bf16)(tf - (float)hi);
  }
}

// K3 (the fused routing pass): per (b, s-chunk of 64):
//   agr[s,n] = x[s,:].t[n,:] via MFMA (t in bf16 hi+lo; x bf16)
//   c = softmax over n (in regs, exact fp32)
//   p[n,d] = c^T @ x via MFMA (c split bf16 hi+lo) -> p_part[b][chunk][n][d]
extern "C" __global__ __launch_bounds__(256) void k_pass(
    const float* __restrict__ x, const __bf16* __restrict__ t_bhi,
    const __bf16* __restrict__ t_blo, float* __restrict__ p_part) {
  __shared__ __align__(16) __bf16 x_lds[SCHUNK_ * XS_];
  __shared__ __align__(16) __bf16 th_lds[N_ * TS_];
  __shared__ __align__(16) __bf16 tl_lds[N_ * TS_];
  __shared__ __align__(16) __bf16 c_Th[N_ * CS_];
  __shared__ __align__(16) __bf16 c_Tl[N_ * CS_];
  const int b = blockIdx.x, ch = blockIdx.y;
  const int t = threadIdx.x, w = t >> 6, lane = t & 63;
  const int quad = lane >> 4, l16 = lane & 15;

  // stage t (hi/lo): 8192 bf16 each
  #pragma unroll
  for (int e = 0; e < 4; ++e) {
    int idx = e * 2048 + t * 8;
    int n = idx >> 8, d = idx & 255;
    *(uint4*)(th_lds + n * TS_ + d) = *(const uint4*)(t_bhi + (size_t)b * 8192 + idx);
    *(uint4*)(tl_lds + n * TS_ + d) = *(const uint4*)(t_blo + (size_t)b * 8192 + idx);
  }
  // stage x rows (fp32 -> bf16)
  const float* xb = x + ((size_t)b * S_ + ch * SCHUNK_) * D_;
  #pragma unroll
  for (int i = 0; i < 16; ++i) {
    int pos = i * 1024 + t * 4;
    int row = pos >> 8, col = pos & 255;
    float4 f = *(const float4*)(xb + row * D_ + col);
    bf16x4 p4;
    p4[0] = (__bf16)f.x; p4[1] = (__bf16)f.y; p4[2] = (__bf16)f.z; p4[3] = (__bf16)f.w;
    *(bf16x4*)(x_lds + row * XS_ + col) = p4;
  }
  __syncthreads();

  // ---- agreement GEMM: A=t (M=n), B=x (N'=s), K=256. wave w owns s-tile w*16.
  floatx4 acc[2];
  acc[0] = (floatx4){0.f, 0.f, 0.f, 0.f};
  acc[1] = (floatx4){0.f, 0.f, 0.f, 0.f};
  const int sbase = w * 16;
  #pragma unroll
  for (int k0 = 0; k0 < 256; k0 += 32) {
    int ks = k0 + quad * 8;
    bf16x8 bfrag = *(const bf16x8*)(x_lds + (sbase + l16) * XS_ + ks);
    #pragma unroll
    for (int i = 0; i < 2; ++i) {
      bf16x8 ah = *(const bf16x8*)(th_lds + (i * 16 + l16) * TS_ + ks);
      bf16x8 al = *(const bf16x8*)(tl_lds + (i * 16 + l16) * TS_ + ks);
      acc[i] = __builtin_amdgcn_mfma_f32_16x16x32_bf16(ah, bfrag, acc[i], 0, 0, 0);
      acc[i] = __builtin_amdgcn_mfma_f32_16x16x32_bf16(al, bfrag, acc[i], 0, 0, 0);
    }
  }
  // ---- softmax over n for s = sbase + l16 (vals: i in {0,1} x reg in 0..3, + quads)
  float mx = -1e30f;
  #pragma unroll
  for (int i = 0; i < 2; ++i)
    #pragma unroll
    for (int r = 0; r < 4; ++r) mx = fmaxf(mx, acc[i][r]);
  mx = fmaxf(mx, __shfl_xor(mx, 16));
  mx = fmaxf(mx, __shfl_xor(mx, 32));
  float e_[2][4];
  float ss = 0.f;
  #pragma unroll
  for (int i = 0; i < 2; ++i)
    #pragma unroll
    for (int r = 0; r < 4; ++r) { e_[i][r] = __expf(acc[i][r] - mx); ss += e_[i][r]; }
  ss += __shfl_xor(ss, 16);
  ss += __shfl_xor(ss, 32);
  float inv = 1.f / ss;
  #pragma unroll
  for (int i = 0; i < 2; ++i)
    #pragma unroll
    for (int r = 0; r < 4; ++r) {
      float cv = e_[i][r] * inv;
      __bf16 chi = (__bf16)cv;
      int o = (i * 16 + quad * 4 + r) * CS_ + sbase + l16;
      c_Th[o] = chi;
      c_Tl[o] = (__bf16)(cv - (float)chi);
    }
  __syncthreads();

  // ---- y GEMM: p[n,d] = c^T @ x. A=c_T (M=n, K=s=64), B=x cols (N'=d).
  // wave w owns d-range w*64 (4 tiles of 16).
  floatx4 acc2[2][4];
  #pragma unroll
  for (int i = 0; i < 2; ++i)
    #pragma unroll
    for (int dt = 0; dt < 4; ++dt) acc2[i][dt] = (floatx4){0.f, 0.f, 0.f, 0.f};
  const int dbase = w * 64;
  #pragma unroll
  for (int k0 = 0; k0 < 64; k0 += 32) {
    int ks = k0 + quad * 8;
    bf16x8 ah[2], al[2];
    #pragma unroll
    for (int i = 0; i < 2; ++i) {
      ah[i] = *(const bf16x8*)(c_Th + (i * 16 + l16) * CS_ + ks);
      al[i] = *(const bf16x8*)(c_Tl + (i * 16 + l16) * CS_ + ks);
    }
    #pragma unroll
    for (int dt = 0; dt < 4; ++dt) {
      bf16x8 bb;
      #pragma unroll
      for (int j8 = 0; j8 < 8; ++j8)
        bb[j8] = x_lds[(ks + j8) * XS_ + dbase + dt * 16 + l16];
      #pragma unroll
      for (int i = 0; i < 2; ++i) {
        acc2[i][dt] = __builtin_amdgcn_mfma_f32_16x16x32_bf16(ah[i], bb, acc2[i][dt], 0, 0, 0);
        acc2[i][dt] = __builtin_amdgcn_mfma_f32_16x16x32_bf16(al[i], bb, acc2[i][dt], 0, 0, 0);
      }
    }
  }
  // store p partials: [b][ch][n][d]
  float* pp = p_part + ((size_t)b * CHUNKS_ + ch) * (N_ * D_);
  #pragma unroll
  for (int i = 0; i < 2; ++i)
    #pragma unroll
    for (int dt = 0; dt < 4; ++dt)
      #pragma unroll
      for (int r = 0; r < 4; ++r) {
        int n = i * 16 + quad * 4 + r;
        int d = dbase + dt * 16 + l16;
        pp[n * D_ + d] = acc2[i][dt][r];
      }
}

extern "C" void kernel_launch(void* const* d_in, const int* in_sizes, int n_in,
                              void* d_out, int out_size, void* d_ws, size_t ws_size,
                              hipStream_t stream) {
  const float* x = (const float*)d_in[0];   // [B,S,D]
  const float* W = (const float*)d_in[1];   // [N,D,C]
  float* out = (float*)d_out;               // [B,N,C]

  // Workspace (~18.5 MB):
  char* ws = (char*)d_ws;
  float* xsum_part = (float*)ws;                              // 32*16*256*4 = 512 KB
  float* p_part = xsum_part + B_ * XP_ * D_;                  // 32*16*32*256*4 = 16 MB
  float* t_fp = p_part + (size_t)B_ * CHUNKS_ * N_ * D_;      // 1 MB
  __bf16* t_bhi = (__bf16*)(t_fp + B_ * N_ * D_);             // 512 KB
  __bf16* t_blo = t_bhi + B_ * N_ * D_;                       // 512 KB

  // iter 0: xsum -> s1 = (1/N) xsum@W -> v1 -> t1 = W@v1
  k_xsum<<<dim3(B_, XP_), 256, 0, stream>>>(x, xsum_part);
  k_small<<<dim3(B_, N_), 256, 0, stream>>>(
      xsum_part, W, t_fp, t_bhi, t_blo, nullptr,
      XP_, XP_ * D_, D_, 0, 1.f / 32.f, 0, 0);

  // iter 1: agr = x.t1 -> c2 -> y1 partials; s2 = y1@W -> v2; t12 = t1 + W@v2
  k_pass<<<dim3(B_, CHUNKS_), 256, 0, stream>>>(x, t_bhi, t_blo, p_part);
  k_small<<<dim3(B_, N_), 256, 0, stream>>>(
      p_part, W, t_fp, t_bhi, t_blo, nullptr,
      CHUNKS_, CHUNKS_ * N_ * D_, N_ * D_, D_, 1.f, 1, 0);

  // iter 2: agr = x.(t1+t2) -> c3 -> y2 partials; s3 = y2@W -> squash -> out
  k_pass<<<dim3(B_, CHUNKS_), 256, 0, stream>>>(x, t_bhi, t_blo, p_part);
  k_small<<<dim3(B_, N_), 256, 0, stream>>>(
      p_part, W, t_fp, t_bhi, t_blo, out,
      CHUNKS_, CHUNKS_ * N_ * D_, N_ * D_, D_, 1.f, 0, 1);
}

// Round 6
// 157.915 us; speedup vs baseline: 1.5254x; 1.0171x over previous
//
#include <hip/hip_runtime.h>
#include <math.h>

namespace {
constexpr int B_ = 32, S_ = 1024, D_ = 256, N_ = 32, C_ = 64;
constexpr int NC_ = N_ * C_;  // 2048
constexpr int XP_ = 16;       // xsum partials per b

typedef __bf16 bf16x8 __attribute__((ext_vector_type(8)));
typedef __bf16 bf16x4 __attribute__((ext_vector_type(4)));
typedef float floatx4 __attribute__((ext_vector_type(4)));

constexpr int XS_ = 264;  // x_lds row stride
constexpr int TS_ = 264;  // t_lds row stride
constexpr int CS_ = 72;   // c_T row stride (s 64 + 8 pad)
}  // namespace

// K1: per (b, s-chunk): xsum partials + x -> bf16 staging in ws.
extern "C" __global__ __launch_bounds__(256) void k_stage(
    const float* __restrict__ x, float* __restrict__ xsum_part,
    __bf16* __restrict__ xb_ws) {
  const int b = blockIdx.x, sb = blockIdx.y, t = threadIdx.x;
  const float* xb = x + ((size_t)b * S_ + sb * 64) * D_;
  float a = 0.f;
  #pragma unroll 8
  for (int s = 0; s < 64; ++s) a += xb[s * D_ + t];
  xsum_part[((size_t)b * XP_ + sb) * D_ + t] = a;

  __bf16* xo = xb_ws + ((size_t)(b * XP_ + sb)) * (64 * D_);
  #pragma unroll
  for (int i = 0; i < 16; ++i) {
    int pos = i * 1024 + t * 4;
    float4 f = *(const float4*)(xb + pos);
    bf16x4 p4;
    p4[0] = (__bf16)f.x; p4[1] = (__bf16)f.y;
    p4[2] = (__bf16)f.z; p4[3] = (__bf16)f.w;
    *(bf16x4*)(xo + pos) = p4;
  }
}

// K2 (small chain) per (b,n):
//   zloc[d] = sum_p z[...]  (P partials; P=1 for direct y rows)
//   s[c] = scale * zloc@W[n];  v = squash(s)
//   final: write v to vout;  else: t = W[n]@v (+= old t if accum) -> fp32 + bf16 hi/lo
//   yzero: zero this block's 256-float row of the NEXT pass's y accumulator.
extern "C" __global__ __launch_bounds__(256) void k_small(
    const float* __restrict__ z, const float* __restrict__ W,
    float* __restrict__ t_fp, __bf16* __restrict__ t_bhi,
    __bf16* __restrict__ t_blo, float* __restrict__ vout,
    float* __restrict__ yzero,
    int P, int zb, int zp, int zn, float scale, int accum, int final_) {
  __shared__ float zloc[256];
  __shared__ float sq_red[4][64];
  __shared__ float v_lds[64];
  const int b = blockIdx.x, n = blockIdx.y, t = threadIdx.x;

  float a = 0.f;
  for (int p = 0; p < P; ++p) a += z[(size_t)b * zb + (size_t)p * zp + n * zn + t];
  zloc[t] = a;
  if (yzero) yzero[((size_t)b * N_ + n) * D_ + t] = 0.f;
  __syncthreads();

  const int c = t & 63, dq = t >> 6;
  const float* Wn = W + (size_t)n * (D_ * C_);
  float s = 0.f;
  #pragma unroll 8
  for (int dd = 0; dd < 64; ++dd) {
    int d = dq * 64 + dd;
    s += zloc[d] * Wn[d * 64 + c];
  }
  sq_red[dq][c] = s;
  __syncthreads();

  if (t < 64) {
    float sc = (sq_red[0][t] + sq_red[1][t] + sq_red[2][t] + sq_red[3][t]) * scale;
    float sq = sc * sc;
    #pragma unroll
    for (int m = 1; m <= 32; m <<= 1) sq += __shfl_xor(sq, m);
    float scl = sq / ((1.f + sq) * sqrtf(sq + 1e-8f));
    float v = sc * scl;
    v_lds[t] = v;
    if (final_) vout[(size_t)b * NC_ + n * 64 + t] = v;
  }
  __syncthreads();

  if (!final_) {
    const float4* W4 = (const float4*)Wn + t * 16;
    float acc = 0.f;
    #pragma unroll
    for (int q = 0; q < 16; ++q) {
      float4 wv = W4[q];
      acc += wv.x * v_lds[q * 4] + wv.y * v_lds[q * 4 + 1] +
             wv.z * v_lds[q * 4 + 2] + wv.w * v_lds[q * 4 + 3];
    }
    size_t idx = ((size_t)b * N_ + n) * D_ + t;
    float tf = acc + (accum ? t_fp[idx] : 0.f);
    t_fp[idx] = tf;
    __bf16 hi = (__bf16)tf;
    t_bhi[idx] = hi;
    t_blo[idx] = (__bf16)(tf - (float)hi);
  }
}

// K3 (routing pass) per (b, s-chunk of 64):
//   agr[s,n] = x.t via MFMA (t bf16 hi+lo) -> softmax over n ->
//   y[b,n,d] += c^T @ x via MFMA (c bf16 hi+lo), fp32 atomics.
extern "C" __global__ __launch_bounds__(256) void k_pass(
    const __bf16* __restrict__ xb_ws, const __bf16* __restrict__ t_bhi,
    const __bf16* __restrict__ t_blo, float* __restrict__ y) {
  __shared__ __align__(16) __bf16 x_lds[64 * XS_];
  __shared__ __align__(16) __bf16 th_lds[N_ * TS_];
  __shared__ __align__(16) __bf16 tl_lds[N_ * TS_];
  __shared__ __align__(16) __bf16 c_Th[N_ * CS_];
  __shared__ __align__(16) __bf16 c_Tl[N_ * CS_];
  const int b = blockIdx.x, ch = blockIdx.y;
  const int t = threadIdx.x, w = t >> 6, lane = t & 63;
  const int quad = lane >> 4, l16 = lane & 15;

  // stage t hi/lo (8192 bf16 each, per b)
  #pragma unroll
  for (int e = 0; e < 4; ++e) {
    int idx = e * 2048 + t * 8;
    int n = idx >> 8, d = idx & 255;
    *(uint4*)(th_lds + n * TS_ + d) = *(const uint4*)(t_bhi + (size_t)b * 8192 + idx);
    *(uint4*)(tl_lds + n * TS_ + d) = *(const uint4*)(t_blo + (size_t)b * 8192 + idx);
  }
  // stage x (already bf16 in ws)
  const __bf16* xsrc = xb_ws + ((size_t)(b * XP_ + ch)) * (64 * D_);
  #pragma unroll
  for (int e = 0; e < 8; ++e) {
    int idx = e * 2048 + t * 8;
    int row = idx >> 8, col = idx & 255;
    *(uint4*)(x_lds + row * XS_ + col) = *(const uint4*)(xsrc + idx);
  }
  __syncthreads();

  // agreement GEMM: A=t (m=n), B=x (n'=s), K=256; wave w owns s-tile w*16
  floatx4 acc[2];
  acc[0] = (floatx4){0.f, 0.f, 0.f, 0.f};
  acc[1] = (floatx4){0.f, 0.f, 0.f, 0.f};
  const int sbase = w * 16;
  #pragma unroll
  for (int k0 = 0; k0 < 256; k0 += 32) {
    int ks = k0 + quad * 8;
    bf16x8 bfrag = *(const bf16x8*)(x_lds + (sbase + l16) * XS_ + ks);
    #pragma unroll
    for (int i = 0; i < 2; ++i) {
      bf16x8 ah = *(const bf16x8*)(th_lds + (i * 16 + l16) * TS_ + ks);
      bf16x8 al = *(const bf16x8*)(tl_lds + (i * 16 + l16) * TS_ + ks);
      acc[i] = __builtin_amdgcn_mfma_f32_16x16x32_bf16(ah, bfrag, acc[i], 0, 0, 0);
      acc[i] = __builtin_amdgcn_mfma_f32_16x16x32_bf16(al, bfrag, acc[i], 0, 0, 0);
    }
  }
  // softmax over n for s = sbase + l16
  float mx = -1e30f;
  #pragma unroll
  for (int i = 0; i < 2; ++i)
    #pragma unroll
    for (int r = 0; r < 4; ++r) mx = fmaxf(mx, acc[i][r]);
  mx = fmaxf(mx, __shfl_xor(mx, 16));
  mx = fmaxf(mx, __shfl_xor(mx, 32));
  float e_[2][4];
  float ss = 0.f;
  #pragma unroll
  for (int i = 0; i < 2; ++i)
    #pragma unroll
    for (int r = 0; r < 4; ++r) { e_[i][r] = __expf(acc[i][r] - mx); ss += e_[i][r]; }
  ss += __shfl_xor(ss, 16);
  ss += __shfl_xor(ss, 32);
  float inv = 1.f / ss;
  #pragma unroll
  for (int i = 0; i < 2; ++i)
    #pragma unroll
    for (int r = 0; r < 4; ++r) {
      float cv = e_[i][r] * inv;
      __bf16 chi = (__bf16)cv;
      int o = (i * 16 + quad * 4 + r) * CS_ + sbase + l16;
      c_Th[o] = chi;
      c_Tl[o] = (__bf16)(cv - (float)chi);
    }
  __syncthreads();

  // y GEMM: y[n,d] += c^T @ x; wave w owns d-range w*64
  floatx4 acc2[2][4];
  #pragma unroll
  for (int i = 0; i < 2; ++i)
    #pragma unroll
    for (int dt = 0; dt < 4; ++dt) acc2[i][dt] = (floatx4){0.f, 0.f, 0.f, 0.f};
  const int dbase = w * 64;
  #pragma unroll
  for (int k0 = 0; k0 < 64; k0 += 32) {
    int ks = k0 + quad * 8;
    bf16x8 ah[2], al[2];
    #pragma unroll
    for (int i = 0; i < 2; ++i) {
      ah[i] = *(const bf16x8*)(c_Th + (i * 16 + l16) * CS_ + ks);
      al[i] = *(const bf16x8*)(c_Tl + (i * 16 + l16) * CS_ + ks);
    }
    #pragma unroll
    for (int dt = 0; dt < 4; ++dt) {
      bf16x8 bfr;
      #pragma unroll
      for (int j8 = 0; j8 < 8; ++j8)
        bfr[j8] = x_lds[(ks + j8) * XS_ + dbase + dt * 16 + l16];
      #pragma unroll
      for (int i = 0; i < 2; ++i) {
        acc2[i][dt] = __builtin_amdgcn_mfma_f32_16x16x32_bf16(ah[i], bfr, acc2[i][dt], 0, 0, 0);
        acc2[i][dt] = __builtin_amdgcn_mfma_f32_16x16x32_bf16(al[i], bfr, acc2[i][dt], 0, 0, 0);
      }
    }
  }
  #pragma unroll
  for (int i = 0; i < 2; ++i)
    #pragma unroll
    for (int dt = 0; dt < 4; ++dt)
      #pragma unroll
      for (int r = 0; r < 4; ++r) {
        int n = i * 16 + quad * 4 + r;
        int d = dbase + dt * 16 + l16;
        atomicAdd(&y[((size_t)b * N_ + n) * D_ + d], acc2[i][dt][r]);
      }
}

extern "C" void kernel_launch(void* const* d_in, const int* in_sizes, int n_in,
                              void* d_out, int out_size, void* d_ws, size_t ws_size,
                              hipStream_t stream) {
  const float* x = (const float*)d_in[0];   // [B,S,D] fp32
  const float* W = (const float*)d_in[1];   // [N,D,C] fp32
  float* out = (float*)d_out;               // [B,N,C] fp32

  // ws (~21 MB): [xb_ws 16M | xsum_part 512K | y1 1M | y2 1M | t_fp 1M | t_bhi 512K | t_blo 512K]
  char* ws = (char*)d_ws;
  __bf16* xb_ws = (__bf16*)ws;
  float* xsum_part = (float*)(ws + 16777216);
  float* y1 = (float*)(ws + 16777216 + 524288);
  float* y2 = y1 + B_ * N_ * D_;
  float* t_fp = y2 + B_ * N_ * D_;
  __bf16* t_bhi = (__bf16*)(t_fp + B_ * N_ * D_);
  __bf16* t_blo = t_bhi + B_ * N_ * D_;

  // 1) stage x (bf16) + xsum partials
  k_stage<<<dim3(B_, XP_), 256, 0, stream>>>(x, xsum_part, xb_ws);

  // 2) iter 0: s1=(1/N)xsum@W -> v1 -> t1; zero y1
  k_small<<<dim3(B_, N_), 256, 0, stream>>>(
      xsum_part, W, t_fp, t_bhi, t_blo, nullptr, y1,
      XP_, XP_ * D_, D_, 0, 1.f / 32.f, 0, 0);

  // 3) pass 1: y1 += c2^T @ x
  k_pass<<<dim3(B_, XP_), 256, 0, stream>>>(xb_ws, t_bhi, t_blo, y1);

  // 4) s2=y1@W -> v2 -> t12 = t1 + W@v2; zero y2
  k_small<<<dim3(B_, N_), 256, 0, stream>>>(
      y1, W, t_fp, t_bhi, t_blo, nullptr, y2,
      1, N_ * D_, 0, D_, 1.f, 1, 0);

  // 5) pass 2: y2 += c3^T @ x
  k_pass<<<dim3(B_, XP_), 256, 0, stream>>>(xb_ws, t_bhi, t_blo, y2);

  // 6) s3=y2@W -> squash -> out
  k_small<<<dim3(B_, N_), 256, 0, stream>>>(
      y2, W, t_fp, t_bhi, t_blo, out, nullptr,
      1, N_ * D_, 0, D_, 1.f, 0, 1);
}